// Round 1
// baseline (38.379 us; speedup 1.0000x reference)
//
#include <hip/hip_runtime.h>

// LocalDE: im2col patches (C=3,K=3 -> D=27) then all upper-triangular
// pairwise products (378) per position. Output [B, L*378] fp32, 186 MB.
// Write-BW bound; one wave per (b,l), LDS-staged patch, float2 stores.

#define B_    32
#define C_    3
#define H_    64
#define W_    64
#define HOUT  62
#define WOUT  62
#define L_    (HOUT * WOUT)   // 3844
#define D_    27
#define NPAIR 378             // D*(D+1)/2
#define NP2   189             // NPAIR/2  (pairs of outputs per position)
#define NPOS  (B_ * L_)       // 123008, divisible by 4

__global__ __launch_bounds__(256) void localde_kernel(
    const float* __restrict__ x, float* __restrict__ out) {
  __shared__ unsigned int tab[NP2];   // packed (i0 | j0<<8 | i1<<16 | j1<<24)
  __shared__ float pbuf[4][28];       // per-wave patch (27 + pad)

  const int tid  = threadIdx.x;
  const int lane = tid & 63;
  const int wv   = tid >> 6;

  // Build the pair-index table once per block (cheap; 189 entries / 256 thr).
  for (int t = tid; t < NP2; t += 256) {
    int pp = 2 * t;
    int i = 0, s = 0;
    while (s + (D_ - i) <= pp) { s += (D_ - i); ++i; }
    int j = i + (pp - s);
    unsigned int packed = (unsigned)i | ((unsigned)j << 8);
    ++pp;  // second pair of this word; continue scan from (i, s)
    while (s + (D_ - i) <= pp) { s += (D_ - i); ++i; }
    j = i + (pp - s);
    packed |= ((unsigned)i << 16) | ((unsigned)j << 24);
    tab[t] = packed;
  }

  const int gidx = blockIdx.x * 4 + wv;   // linear index over B*L positions
  if (gidx < NPOS && lane < D_) {
    int b  = gidx / L_;
    int l  = gidx - b * L_;
    int oh = l / WOUT;
    int ow = l - oh * WOUT;
    int c  = lane / 9;
    int r  = lane - c * 9;
    int ki = r / 3;
    int kj = r - ki * 3;
    pbuf[wv][lane] = x[((b * C_ + c) * H_ + oh + ki) * W_ + ow + kj];
  }
  __syncthreads();
  if (gidx >= NPOS) return;

  // 189 float2 outputs per position; 64 lanes x 3 iters. 8B-aligned base
  // (gidx*1512 bytes), so float2 stores are legal and fully coalesced.
  float2* __restrict__ outp = (float2*)(out + (size_t)gidx * NPAIR);
  const float* __restrict__ p = pbuf[wv];
#pragma unroll
  for (int t = 0; t < 3; ++t) {
    int pp2 = lane + t * 64;
    if (pp2 < NP2) {
      unsigned int tw = tab[pp2];
      float2 v;
      v.x = p[tw & 255u] * p[(tw >> 8) & 255u];
      v.y = p[(tw >> 16) & 255u] * p[tw >> 24];
      outp[pp2] = v;
    }
  }
}

extern "C" void kernel_launch(void* const* d_in, const int* in_sizes, int n_in,
                              void* d_out, int out_size, void* d_ws, size_t ws_size,
                              hipStream_t stream) {
  const float* x = (const float*)d_in[0];
  float* out = (float*)d_out;
  const int grid = NPOS / 4;  // 30752 blocks, 4 positions each
  localde_kernel<<<grid, 256, 0, stream>>>(x, out);
}